// Round 11
// baseline (224.112 us; speedup 1.0000x reference)
//
#include <hip/hip_runtime.h>
#include <math.h>

// Problem constants
#define S_N 16
#define D_N 256
#define H_N 128
#define K_N 32
#define B_N 16384

typedef __attribute__((ext_vector_type(8))) short bf16x8;
typedef __attribute__((ext_vector_type(4))) float f32x4;
typedef __attribute__((ext_vector_type(16))) float f32x16;

#define MFMA16(a, b, c) __builtin_amdgcn_mfma_f32_16x16x32_bf16(a, b, c, 0, 0, 0)
#define MFMA32(a, b, c) __builtin_amdgcn_mfma_f32_32x32x16_bf16(a, b, c, 0, 0, 0)
#define SWZ(r)  ((unsigned)(((r) & 15) << 4))
#define SWZ8(r) ((unsigned)(((r) & 7) << 4))

static __device__ __forceinline__ unsigned short f2bf(float f) {
  union { float f; unsigned u; } v; v.f = f;
  unsigned r = v.u + 0x7FFFu + ((v.u >> 16) & 1u);  // RNE
  return (unsigned short)(r >> 16);
}

// ---------------- merged pre-pass (unchanged) ----------------
__global__ __launch_bounds__(256)
void lsi_prep(const float* __restrict__ W1, const float* __restrict__ W2,
              const float* __restrict__ Wc1, const float* __restrict__ b2,
              const float* __restrict__ bc1,
              unsigned short* __restrict__ W1t,
              unsigned short* __restrict__ W2t,
              unsigned short* __restrict__ Wft,
              float* __restrict__ bcf)
{
  const int bid = blockIdx.x;
  if (bid < 1024) {
    __shared__ float t[32][33];
    const float* src; unsigned short* dst; int R, C, r0, c0;
    if (bid < 512) {
      int s = bid >> 5, tt = bid & 31;
      R = 256; C = 128; r0 = (tt >> 2) * 32; c0 = (tt & 3) * 32;
      src = W1 + (size_t)s * 256 * 128; dst = W1t + (size_t)s * 128 * 256;
    } else {
      int s = (bid - 512) >> 5, tt = (bid - 512) & 31;
      R = 128; C = 256; r0 = (tt >> 3) * 32; c0 = (tt & 7) * 32;
      src = W2 + (size_t)s * 128 * 256; dst = W2t + (size_t)s * 256 * 128;
    }
    int li = threadIdx.x >> 5, lj = threadIdx.x & 31;
    #pragma unroll
    for (int i = 0; i < 4; ++i)
      t[li + i * 8][lj] = src[(size_t)(r0 + li + i * 8) * C + c0 + lj];
    __syncthreads();
    #pragma unroll
    for (int i = 0; i < 4; ++i)
      dst[(size_t)(c0 + li + i * 8) * R + r0 + lj] = f2bf(t[lj][li + i * 8]);
    return;
  }
  const int q  = bid - 1024;
  const int s  = q >> 3, hb = q & 7;
  const int t  = threadIdx.x;
  const int hh = hb * 16 + (t >> 4);
  const int kb = (t & 15) * 2;
  const float* w2r = W2 + ((size_t)s * H_N + hh) * D_N;
  const float* wc1 = Wc1 + (size_t)s * D_N * K_N;
  float a0 = 0.f, a1 = 0.f;
  for (int d = 0; d < D_N; ++d) {
    float wv = w2r[d];
    a0 = fmaf(wv, wc1[d * K_N + kb], a0);
    a1 = fmaf(wv, wc1[d * K_N + kb + 1], a1);
  }
  Wft[((size_t)s * K_N + kb) * H_N + hh]     = f2bf(a0);
  Wft[((size_t)s * K_N + kb + 1) * H_N + hh] = f2bf(a1);
  if (hb == 0 && t < K_N) {
    float a = bc1[s * K_N + t];
    for (int d = 0; d < D_N; ++d)
      a = fmaf(b2[s * D_N + d], wc1[d * K_N + t], a);
    bcf[s * K_N + t] = a;
  }
}

// ---------------- stage1: H = relu(x.W1+b1), raw conf z ----------------
// grid 8192 = (rowgroup 512 x source 16), 256 thr (4 waves), 24 KB LDS,
// no persistent acc -> high occupancy (LDS-bound ~6 blocks/CU).
// XCD-aware mapping: all 16 sources of a rowgroup land on one XCD (x-tile L2 reuse).
__global__ __launch_bounds__(256)
void lsi_stage1(const float* __restrict__ x, const float* __restrict__ b1,
                const unsigned short* __restrict__ W1t,
                const unsigned short* __restrict__ Wft,
                const float* __restrict__ bcf, const float* __restrict__ Wc2,
                unsigned short* __restrict__ H, float* __restrict__ z_t)
{
  __shared__ unsigned short x_lds[32 * D_N];   // 16 KB, swizzled
  __shared__ unsigned short h_lds[32 * H_N];   // 8 KB, swizzled

  const int p   = blockIdx.x;
  const int s   = (p >> 3) & 15;
  const int rg  = (p & 7) + 8 * (p >> 7);      // blocks with equal p%8 share XCD
  const int b0  = rg * 32;

  const int tid = threadIdx.x;
  const int w   = tid >> 6;       // wave 0..3
  const int l   = tid & 63;
  const int l31 = l & 31;
  const int hi  = l >> 5;
  const int rA  = l & 15;
  const int g   = l >> 4;         // 0..3

  // ---- stage x tile [32 x 256] -> bf16 LDS ----
  {
    int row = tid >> 3;                 // 0..31
    int c0  = (tid & 7) * 32;
    const float* xr = x + (size_t)(b0 + row) * D_N + c0;
    #pragma unroll
    for (int cc = 0; cc < 4; ++cc) {
      float4 f0 = *(const float4*)(xr + cc * 8);
      float4 f1 = *(const float4*)(xr + cc * 8 + 4);
      bf16x8 u;
      u[0] = f2bf(f0.x); u[1] = f2bf(f0.y); u[2] = f2bf(f0.z); u[3] = f2bf(f0.w);
      u[4] = f2bf(f1.x); u[5] = f2bf(f1.y); u[6] = f2bf(f1.z); u[7] = f2bf(f1.w);
      unsigned off = (unsigned)(row * 512 + (c0 + cc * 8) * 2) ^ SWZ(row);
      *(bf16x8*)((char*)x_lds + off) = u;
    }
  }
  __syncthreads();

  // ---- GEMM1: wave w -> hcols [32w,32w+32), rows 0..31, K=256 ----
  {
    const int hcol = w * 32 + l31;
    f32x16 acc1;
    #pragma unroll
    for (int i = 0; i < 16; ++i) acc1[i] = 0.f;
    const unsigned short* B1 = W1t + ((size_t)s * H_N + hcol) * D_N + hi * 8;
    #pragma unroll
    for (int kf = 0; kf < 16; ++kf) {
      bf16x8 bfr = *(const bf16x8*)(B1 + kf * 16);
      unsigned off = (unsigned)(l31 * 512 + kf * 32 + hi * 16) ^ SWZ(l31);
      bf16x8 afr = *(const bf16x8*)((const char*)x_lds + off);
      acc1 = MFMA32(afr, bfr, acc1);
    }
    const float b1v = b1[s * H_N + hcol];
    #pragma unroll
    for (int r = 0; r < 16; ++r) {
      int row = (r & 3) + 8 * (r >> 2) + 4 * hi;
      float v = fmaxf(acc1[r] + b1v, 0.f);
      unsigned off = (unsigned)(row * 256 + hcol * 2) ^ SWZ(row);
      *(unsigned short*)((char*)h_lds + off) = f2bf(v);
    }
  }
  __syncthreads();

  if (w < 2) {
    // ---- conf: wave w -> rows [16w,16w+16), raw z (no sigmoid/bc2 here) ----
    f32x4 acc3[2];
    acc3[0] = (f32x4){0.f, 0.f, 0.f, 0.f};
    acc3[1] = (f32x4){0.f, 0.f, 0.f, 0.f};
    const unsigned short* Bf = Wft + ((size_t)s * K_N + rA) * H_N + g * 8;
    #pragma unroll
    for (int ks = 0; ks < 4; ++ks) {
      int row = w * 16 + rA;
      unsigned off = (unsigned)(row * 256 + (ks * 32 + g * 8) * 2) ^ SWZ(row);
      bf16x8 afr = *(const bf16x8*)((const char*)h_lds + off);
      acc3[0] = MFMA16(afr, *(const bf16x8*)(Bf + ks * 32), acc3[0]);
      acc3[1] = MFMA16(afr, *(const bf16x8*)(Bf + 16 * H_N + ks * 32), acc3[1]);
    }
    const float bcf0 = bcf[s * K_N + rA],  bcf1 = bcf[s * K_N + 16 + rA];
    const float wc20 = Wc2[s * K_N + rA],  wc21 = Wc2[s * K_N + 16 + rA];
    float pz[4];
    #pragma unroll
    for (int i = 0; i < 4; ++i)
      pz[i] = fmaxf(acc3[0][i] + bcf0, 0.f) * wc20 +
              fmaxf(acc3[1][i] + bcf1, 0.f) * wc21;
    #pragma unroll
    for (int m = 1; m < 16; m <<= 1)
      #pragma unroll
      for (int i = 0; i < 4; ++i)
        pz[i] += __shfl_xor(pz[i], m);
    if (rA == 0) {
      #pragma unroll
      for (int i = 0; i < 4; ++i)
        z_t[(size_t)s * B_N + b0 + w * 16 + g * 4 + i] = pz[i];
    }
  } else {
    // ---- waves 2-3: copy h_lds -> H[s] (coalesced b128) ----
    const int u = tid - 128;             // 0..127
    unsigned short* Hs = H + (size_t)s * B_N * H_N;
    #pragma unroll
    for (int i = 0; i < 4; ++i) {
      int c   = u + 128 * i;             // 16B-chunk id 0..511
      int row = c >> 4;
      int cc  = c & 15;
      unsigned off = (unsigned)(row * 256 + cc * 16) ^ SWZ(row);
      bf16x8 v = *(const bf16x8*)((const char*)h_lds + off);
      *(bf16x8*)(Hs + (size_t)(b0 + row) * H_N + cc * 8) = v;
    }
  }
}

// ---------------- norm: w_t = lam*sigmoid(z+bc2) / (sum + 1e-6) ----------------
__global__ __launch_bounds__(256)
void lsi_norm(const float* __restrict__ z_t, const float* __restrict__ lam,
              const float* __restrict__ bc2, float* __restrict__ w_t)
{
  const int b = blockIdx.x * 256 + threadIdx.x;
  float cv[S_N];
  float sum = 0.f;
  #pragma unroll
  for (int s = 0; s < S_N; ++s) {
    float c = lam[s] / (1.f + __expf(-(z_t[(size_t)s * B_N + b] + bc2[s])));
    cv[s] = c;
    sum += c;
  }
  const float winv = 1.f / (sum + 1e-6f);
  #pragma unroll
  for (int s = 0; s < S_N; ++s)
    w_t[(size_t)s * B_N + b] = cv[s] * winv;
}

// ---------------- stage2: out = sum_s w.(H_s.W2[s] + b2) ----------------
// grid 512 (32 rows each), 256 thr (4 waves), NO LDS, NO barriers.
// wave w -> dcols [64w,64w+64) as two 32x32 tiles; K=128 per source.
__global__ __launch_bounds__(256)
void lsi_stage2(const unsigned short* __restrict__ H,
                const unsigned short* __restrict__ W2t,
                const float* __restrict__ b2, const float* __restrict__ w_t,
                float* __restrict__ out)
{
  const int b0  = blockIdx.x * 32;
  const int tid = threadIdx.x;
  const int w   = tid >> 6;
  const int l   = tid & 63;
  const int l31 = l & 31;
  const int hi  = l >> 5;
  const int dc0 = w * 64 + l31;
  const int dc1 = dc0 + 32;

  f32x16 oa0, oa1;
  #pragma unroll
  for (int i = 0; i < 16; ++i) { oa0[i] = 0.f; oa1[i] = 0.f; }

  for (int s = 0; s < S_N; ++s) {
    const unsigned short* Hs  = H + ((size_t)s * B_N + b0 + l31) * H_N + hi * 8;
    const unsigned short* B2a = W2t + ((size_t)s * D_N + dc0) * H_N + hi * 8;
    const unsigned short* B2b = W2t + ((size_t)s * D_N + dc1) * H_N + hi * 8;
    f32x16 t0, t1;
    #pragma unroll
    for (int i = 0; i < 16; ++i) { t0[i] = 0.f; t1[i] = 0.f; }
    #pragma unroll
    for (int kf = 0; kf < 8; ++kf) {
      bf16x8 afr = *(const bf16x8*)(Hs + kf * 16);
      t0 = MFMA32(afr, *(const bf16x8*)(B2a + kf * 16), t0);
      t1 = MFMA32(afr, *(const bf16x8*)(B2b + kf * 16), t1);
    }
    const float b20 = b2[s * D_N + dc0];
    const float b21 = b2[s * D_N + dc1];
    #pragma unroll
    for (int q = 0; q < 4; ++q) {
      f32x4 w4 = *(const f32x4*)(w_t + (size_t)s * B_N + b0 + q * 8 + hi * 4);
      #pragma unroll
      for (int i = 0; i < 4; ++i) {
        oa0[q * 4 + i] += w4[i] * (t0[q * 4 + i] + b20);
        oa1[q * 4 + i] += w4[i] * (t1[q * 4 + i] + b21);
      }
    }
  }
  #pragma unroll
  for (int q = 0; q < 4; ++q)
    #pragma unroll
    for (int i = 0; i < 4; ++i) {
      int row = q * 8 + hi * 4 + i;
      out[(size_t)(b0 + row) * D_N + dc0] = oa0[q * 4 + i];
      out[(size_t)(b0 + row) * D_N + dc1] = oa1[q * 4 + i];
    }
}

// ---------------- fallback monolith (R9, 107.6us) if ws too small ----------------
__global__ __launch_bounds__(512, 2)
void lsi_mono(const float* __restrict__ x, const float* __restrict__ b1,
              const float* __restrict__ b2, const float* __restrict__ Wc2,
              const float* __restrict__ bc2, const float* __restrict__ lam,
              const unsigned short* __restrict__ W1t,
              const unsigned short* __restrict__ W2t,
              const unsigned short* __restrict__ Wft,
              const float* __restrict__ bcf, float* __restrict__ out)
{
  __shared__ unsigned short x_lds[64 * D_N];
  __shared__ unsigned short h_lds[2][64 * H_N];
  __shared__ float cw_lds[2][64];
  __shared__ float wsum_lds[64];

  const int tid = threadIdx.x;
  const int w   = tid >> 6;
  const int l   = tid & 63;
  const int rA  = l & 15;
  const int g   = l >> 4;
  const int k8  = g * 8;
  const int b0  = blockIdx.x * 64;

  {
    int row = tid >> 3;
    int c0  = (tid & 7) * 32;
    const float* xr = x + (size_t)(b0 + row) * D_N + c0;
    #pragma unroll
    for (int cc = 0; cc < 4; ++cc) {
      float4 f0 = *(const float4*)(xr + cc * 8);
      float4 f1 = *(const float4*)(xr + cc * 8 + 4);
      bf16x8 u;
      u[0] = f2bf(f0.x); u[1] = f2bf(f0.y); u[2] = f2bf(f0.z); u[3] = f2bf(f0.w);
      u[4] = f2bf(f1.x); u[5] = f2bf(f1.y); u[6] = f2bf(f1.z); u[7] = f2bf(f1.w);
      unsigned off = (unsigned)(row * 512 + (c0 + cc * 8) * 2) ^ SWZ8(row);
      *(bf16x8*)((char*)x_lds + off) = u;
    }
  }
  if (tid < 64) wsum_lds[tid] = 0.f;

  f32x4 out_acc[2][4];
  f32x4 acc2[2][4];
  #pragma unroll
  for (int a = 0; a < 2; ++a)
    #pragma unroll
    for (int b = 0; b < 4; ++b)
      out_acc[a][b] = (f32x4){0.f, 0.f, 0.f, 0.f};

  auto do_gemm1 = [&](int s, unsigned short* hw) {
    f32x4 acc1[4];
    #pragma unroll
    for (int rt = 0; rt < 4; ++rt) acc1[rt] = (f32x4){0.f, 0.f, 0.f, 0.f};
    const unsigned short* B1 = W1t + ((size_t)s * H_N + w * 16 + rA) * D_N + k8;
    #pragma unroll
    for (int ks = 0; ks < 8; ++ks) {
      bf16x8 bfr = *(const bf16x8*)(B1 + ks * 32);
      #pragma unroll
      for (int rt = 0; rt < 4; ++rt) {
        int row = rt * 16 + rA;
        unsigned off = (unsigned)(row * 512 + (ks * 32 + k8) * 2) ^ SWZ8(row);
        bf16x8 afr = *(const bf16x8*)((const char*)x_lds + off);
        acc1[rt] = MFMA16(afr, bfr, acc1[rt]);
      }
    }
    const float b1v = b1[s * H_N + w * 16 + rA];
    #pragma unroll
    for (int rt = 0; rt < 4; ++rt)
      #pragma unroll
      for (int i = 0; i < 4; ++i) {
        float v = fmaxf(acc1[rt][i] + b1v, 0.f);
        int row = rt * 16 + g * 4 + i;
        unsigned off = (unsigned)(row * 256 + (w * 16 + rA) * 2) ^ SWZ8(row);
        *(unsigned short*)((char*)hw + off) = f2bf(v);
      }
  };

  __syncthreads();
  do_gemm1(0, h_lds[0]);
  __syncthreads();

  for (int s = 0; s < S_N; ++s) {
    const unsigned short* hr = (const unsigned short*)h_lds[s & 1];
    if (s > 0) {
      #pragma unroll
      for (int rt = 0; rt < 4; ++rt) {
        f32x4 c4 = *(const f32x4*)&cw_lds[(s + 1) & 1][rt * 16 + g * 4];
        #pragma unroll
        for (int i = 0; i < 4; ++i) {
          out_acc[0][rt][i] += c4[i] * acc2[0][rt][i];
          out_acc[1][rt][i] += c4[i] * acc2[1][rt][i];
        }
      }
    }
    if (w < 4) {
      f32x4 acc3[2];
      acc3[0] = (f32x4){0.f, 0.f, 0.f, 0.f};
      acc3[1] = (f32x4){0.f, 0.f, 0.f, 0.f};
      const unsigned short* Bf = Wft + ((size_t)s * K_N + rA) * H_N + k8;
      #pragma unroll
      for (int ks = 0; ks < 4; ++ks) {
        int row = w * 16 + rA;
        unsigned off = (unsigned)(row * 256 + (ks * 32 + k8) * 2) ^ SWZ8(row);
        bf16x8 afr = *(const bf16x8*)((const char*)hr + off);
        acc3[0] = MFMA16(afr, *(const bf16x8*)(Bf + ks * 32), acc3[0]);
        acc3[1] = MFMA16(afr, *(const bf16x8*)(Bf + 16 * H_N + ks * 32), acc3[1]);
      }
      const float bcf0 = bcf[s * K_N + rA],  bcf1 = bcf[s * K_N + 16 + rA];
      const float wc20 = Wc2[s * K_N + rA],  wc21 = Wc2[s * K_N + 16 + rA];
      float pz[4];
      #pragma unroll
      for (int i = 0; i < 4; ++i)
        pz[i] = fmaxf(acc3[0][i] + bcf0, 0.f) * wc20 +
                fmaxf(acc3[1][i] + bcf1, 0.f) * wc21;
      #pragma unroll
      for (int m = 1; m < 16; m <<= 1)
        #pragma unroll
        for (int i = 0; i < 4; ++i)
          pz[i] += __shfl_xor(pz[i], m);
      if (rA == 0) {
        const float lam_s = lam[s], bc2_s = bc2[s];
        #pragma unroll
        for (int i = 0; i < 4; ++i) {
          float cv = lam_s / (1.f + __expf(-(pz[i] + bc2_s)));
          cw_lds[s & 1][w * 16 + g * 4 + i] = cv;
          wsum_lds[w * 16 + g * 4 + i] += cv;
        }
      }
    }
    #pragma unroll
    for (int a = 0; a < 2; ++a)
      #pragma unroll
      for (int b = 0; b < 4; ++b)
        acc2[a][b] = (f32x4){0.f, 0.f, 0.f, 0.f};
    {
      const unsigned short* B2 = W2t + ((size_t)s * D_N + w * 32 + rA) * H_N + k8;
      #pragma unroll
      for (int ks = 0; ks < 4; ++ks) {
        bf16x8 afr[4];
        #pragma unroll
        for (int rt = 0; rt < 4; ++rt) {
          int row = rt * 16 + rA;
          unsigned off = (unsigned)(row * 256 + (ks * 32 + k8) * 2) ^ SWZ8(row);
          afr[rt] = *(const bf16x8*)((const char*)hr + off);
        }
        #pragma unroll
        for (int ct = 0; ct < 2; ++ct) {
          bf16x8 bfr = *(const bf16x8*)(B2 + ct * 16 * H_N + ks * 32);
          #pragma unroll
          for (int rt = 0; rt < 4; ++rt)
            acc2[ct][rt] = MFMA16(afr[rt], bfr, acc2[ct][rt]);
        }
      }
      float b2v0 = b2[s * D_N + w * 32 + rA];
      float b2v1 = b2[s * D_N + w * 32 + 16 + rA];
      #pragma unroll
      for (int rt = 0; rt < 4; ++rt)
        #pragma unroll
        for (int i = 0; i < 4; ++i) {
          acc2[0][rt][i] += b2v0;
          acc2[1][rt][i] += b2v1;
        }
    }
    if (s + 1 < S_N) do_gemm1(s + 1, h_lds[(s + 1) & 1]);
    __syncthreads();
  }

  #pragma unroll
  for (int rt = 0; rt < 4; ++rt) {
    f32x4 c4 = *(const f32x4*)&cw_lds[(S_N - 1) & 1][rt * 16 + g * 4];
    #pragma unroll
    for (int i = 0; i < 4; ++i) {
      out_acc[0][rt][i] += c4[i] * acc2[0][rt][i];
      out_acc[1][rt][i] += c4[i] * acc2[1][rt][i];
    }
  }
  #pragma unroll
  for (int rt = 0; rt < 4; ++rt) {
    f32x4 w4 = *(const f32x4*)&wsum_lds[rt * 16 + g * 4];
    #pragma unroll
    for (int i = 0; i < 4; ++i) {
      int row = rt * 16 + g * 4 + i;
      float winv = 1.f / (w4[i] + 1e-6f);
      out[(size_t)(b0 + row) * D_N + w * 32 + rA]      = out_acc[0][rt][i] * winv;
      out[(size_t)(b0 + row) * D_N + w * 32 + 16 + rA] = out_acc[1][rt][i] * winv;
    }
  }
}

extern "C" void kernel_launch(void* const* d_in, const int* in_sizes, int n_in,
                              void* d_out, int out_size, void* d_ws, size_t ws_size,
                              hipStream_t stream) {
  const float* x   = (const float*)d_in[0];
  const float* W1  = (const float*)d_in[1];
  const float* b1  = (const float*)d_in[2];
  const float* W2  = (const float*)d_in[3];
  const float* b2  = (const float*)d_in[4];
  const float* Wc1 = (const float*)d_in[5];
  const float* bc1 = (const float*)d_in[6];
  const float* Wc2 = (const float*)d_in[7];
  const float* bc2 = (const float*)d_in[8];
  const float* lam = (const float*)d_in[9];
  float* out = (float*)d_out;

  // ws: W1t 1MB | W2t 1MB | Wft 128KB | bcf 2KB | z_t 1MB | w_t 1MB | H 64MB
  unsigned short* W1t = (unsigned short*)d_ws;
  unsigned short* W2t = W1t + (size_t)S_N * H_N * D_N;
  unsigned short* Wft = W2t + (size_t)S_N * D_N * H_N;
  float* bcf = (float*)(Wft + (size_t)S_N * K_N * H_N);
  float* z_t = bcf + S_N * K_N;
  float* w_t = z_t + (size_t)S_N * B_N;
  unsigned short* H = (unsigned short*)(w_t + (size_t)S_N * B_N);
  size_t need = (size_t)((char*)(H + (size_t)S_N * B_N * H_N) - (char*)d_ws);

  lsi_prep<<<dim3(1152), dim3(256), 0, stream>>>(W1, W2, Wc1, b2, bc1,
                                                 W1t, W2t, Wft, bcf);
  if (ws_size >= need) {
    lsi_stage1<<<dim3(8192), dim3(256), 0, stream>>>(x, b1, W1t, Wft, bcf, Wc2,
                                                     H, z_t);
    lsi_norm<<<dim3(B_N / 256), dim3(256), 0, stream>>>(z_t, lam, bc2, w_t);
    lsi_stage2<<<dim3(B_N / 32), dim3(256), 0, stream>>>(H, W2t, b2, w_t, out);
  } else {
    lsi_mono<<<dim3(B_N / 64), dim3(512), 0, stream>>>(x, b1, b2, Wc2, bc2, lam,
                                                       W1t, W2t, Wft, bcf, out);
  }
}

// Round 12
// 137.833 us; speedup vs baseline: 1.6260x; 1.6260x over previous
//
#include <hip/hip_runtime.h>
#include <math.h>

// Problem constants
#define S_N 16
#define D_N 256
#define H_N 128
#define K_N 32
#define BT  64
#define B_N 16384

typedef __attribute__((ext_vector_type(8))) short bf16x8;
typedef __attribute__((ext_vector_type(4))) short bf16x4;
typedef __attribute__((ext_vector_type(4))) float f32x4;
typedef __attribute__((ext_vector_type(16))) float f32x16;

#define MFMA16(a, b, c) __builtin_amdgcn_mfma_f32_16x16x32_bf16(a, b, c, 0, 0, 0)
#define MFMA32(a, b, c) __builtin_amdgcn_mfma_f32_32x32x16_bf16(a, b, c, 0, 0, 0)
#define SWZ(r) ((unsigned)(((r) & 15) << 4))

static __device__ __forceinline__ unsigned short f2bf(float f) {
  union { float f; unsigned u; } v; v.f = f;
  unsigned r = v.u + 0x7FFFu + ((v.u >> 16) & 1u);  // RNE
  return (unsigned short)(r >> 16);
}

// ---------------- merged pre-pass (unchanged) ----------------
__global__ __launch_bounds__(256)
void lsi_prep(const float* __restrict__ W1, const float* __restrict__ W2,
              const float* __restrict__ Wc1, const float* __restrict__ b2,
              const float* __restrict__ bc1,
              unsigned short* __restrict__ W1t,
              unsigned short* __restrict__ W2t,
              unsigned short* __restrict__ Wft,
              float* __restrict__ bcf)
{
  const int bid = blockIdx.x;
  if (bid < 1024) {
    __shared__ float t[32][33];
    const float* src; unsigned short* dst; int R, C, r0, c0;
    if (bid < 512) {
      int s = bid >> 5, tt = bid & 31;
      R = 256; C = 128; r0 = (tt >> 2) * 32; c0 = (tt & 3) * 32;
      src = W1 + (size_t)s * 256 * 128; dst = W1t + (size_t)s * 128 * 256;
    } else {
      int s = (bid - 512) >> 5, tt = (bid - 512) & 31;
      R = 128; C = 256; r0 = (tt >> 3) * 32; c0 = (tt & 7) * 32;
      src = W2 + (size_t)s * 128 * 256; dst = W2t + (size_t)s * 256 * 128;
    }
    int li = threadIdx.x >> 5, lj = threadIdx.x & 31;
    #pragma unroll
    for (int i = 0; i < 4; ++i)
      t[li + i * 8][lj] = src[(size_t)(r0 + li + i * 8) * C + c0 + lj];
    __syncthreads();
    #pragma unroll
    for (int i = 0; i < 4; ++i)
      dst[(size_t)(c0 + li + i * 8) * R + r0 + lj] = f2bf(t[lj][li + i * 8]);
    return;
  }
  const int q  = bid - 1024;
  const int s  = q >> 3, hb = q & 7;
  const int t  = threadIdx.x;
  const int hh = hb * 16 + (t >> 4);
  const int kb = (t & 15) * 2;
  const float* w2r = W2 + ((size_t)s * H_N + hh) * D_N;
  const float* wc1 = Wc1 + (size_t)s * D_N * K_N;
  float a0 = 0.f, a1 = 0.f;
  for (int d = 0; d < D_N; ++d) {
    float wv = w2r[d];
    a0 = fmaf(wv, wc1[d * K_N + kb], a0);
    a1 = fmaf(wv, wc1[d * K_N + kb + 1], a1);
  }
  Wft[((size_t)s * K_N + kb) * H_N + hh]     = f2bf(a0);
  Wft[((size_t)s * K_N + kb + 1) * H_N + hh] = f2bf(a1);
  if (hb == 0 && t < K_N) {
    float a = bc1[s * K_N + t];
    for (int d = 0; d < D_N; ++d)
      a = fmaf(b2[s * D_N + d], wc1[d * K_N + t], a);
    bcf[s * K_N + t] = a;
  }
}

// ---------------- fused main kernel: TRANSPOSED compute ----------------
// grid 256, block 512 (8 waves), BT=64, 1 barrier/source, dbuf h (R9 sched).
// All GEMMs swapped: C[outcol][brow], A = weights (global), B = activations.
// Lane&31 = batch row; regs = output cols -> packed h-writes (b64), scalar
// cw reads, f32x4 biases, 2-shfl conf reduce. Every MFMA32 has 2 indep chains.
__global__ __launch_bounds__(512, 2)
void lsi_main(const float* __restrict__ x,
              const float* __restrict__ b1,
              const float* __restrict__ b2,
              const float* __restrict__ Wc2,
              const float* __restrict__ bc2,
              const float* __restrict__ lam,
              const unsigned short* __restrict__ W1t,
              const unsigned short* __restrict__ W2t,
              const unsigned short* __restrict__ Wft,
              const float* __restrict__ bcf,
              float* __restrict__ out)
{
  __shared__ __align__(16) unsigned short x_lds[BT * D_N];      // 32 KB
  __shared__ __align__(16) unsigned short h_lds[2][BT * H_N];   // 32 KB
  __shared__ float cw_lds[2][BT];
  __shared__ float wsum_lds[BT];

  const int tid = threadIdx.x;
  const int w   = tid >> 6;
  const int l   = tid & 63;
  const int l31 = l & 31;
  const int hi  = l >> 5;
  const int l15 = l & 15;
  const int g   = l >> 4;
  const int b0  = blockIdx.x * BT;
  const int bt1 = w >> 2;        // GEMM1 brow tile
  const int ct1 = w & 3;         // GEMM1 hcol tile

  // ---- stage x tile [64 x 256] -> bf16 LDS (swizzled) ----
  {
    int row = tid >> 3;
    int c0  = (tid & 7) * 32;
    const float* xr = x + (size_t)(b0 + row) * D_N + c0;
    #pragma unroll
    for (int cc = 0; cc < 4; ++cc) {
      float4 f0 = *(const float4*)(xr + cc * 8);
      float4 f1 = *(const float4*)(xr + cc * 8 + 4);
      bf16x8 u;
      u[0] = f2bf(f0.x); u[1] = f2bf(f0.y); u[2] = f2bf(f0.z); u[3] = f2bf(f0.w);
      u[4] = f2bf(f1.x); u[5] = f2bf(f1.y); u[6] = f2bf(f1.z); u[7] = f2bf(f1.w);
      unsigned off = (unsigned)(row * 512 + (c0 + cc * 8) * 2) ^ SWZ(row);
      *(bf16x8*)((char*)x_lds + off) = u;
    }
  }
  if (tid < BT) wsum_lds[tid] = 0.f;

  f32x16 out_acc[2], acc2[2];
  #pragma unroll
  for (int i = 0; i < 16; ++i) {
    out_acc[0][i] = 0.f; out_acc[1][i] = 0.f;
  }

  // GEMM1(s) swapped: C[hcol][brow]; wave -> (bt1 brow-tile, ct1 hcol-tile)
  auto do_gemm1 = [&](int s, unsigned short* hw) {
    const int brow = bt1 * 32 + l31;
    f32x16 a1a, a1b;
    #pragma unroll
    for (int i = 0; i < 16; ++i) { a1a[i] = 0.f; a1b[i] = 0.f; }
    const unsigned short* A1 = W1t + ((size_t)s * H_N + ct1 * 32 + l31) * D_N + hi * 8;
    const unsigned xbase = (unsigned)(brow * 512 + hi * 16);
    #pragma unroll
    for (int kf = 0; kf < 16; kf += 2) {       // 2 independent chains
      bf16x8 aw0 = *(const bf16x8*)(A1 + kf * 16);
      bf16x8 aw1 = *(const bf16x8*)(A1 + kf * 16 + 16);
      bf16x8 bx0 = *(const bf16x8*)((const char*)x_lds + ((xbase + kf * 32) ^ SWZ(brow)));
      bf16x8 bx1 = *(const bf16x8*)((const char*)x_lds + ((xbase + kf * 32 + 32) ^ SWZ(brow)));
      a1a = MFMA32(aw0, bx0, a1a);
      a1b = MFMA32(aw1, bx1, a1b);
    }
    #pragma unroll
    for (int q = 0; q < 4; ++q) {
      f32x4 b4 = *(const f32x4*)(b1 + s * H_N + ct1 * 32 + q * 8 + hi * 4);
      bf16x4 hv;
      #pragma unroll
      for (int i = 0; i < 4; ++i)
        hv[i] = (short)f2bf(fmaxf(a1a[q * 4 + i] + a1b[q * 4 + i] + b4[i], 0.f));
      unsigned off = (unsigned)(brow * 256 + (ct1 * 32 + q * 8 + hi * 4) * 2) ^ SWZ(brow);
      *(bf16x4*)((char*)hw + off) = hv;   // packed b64 write
    }
  };

  __syncthreads();             // x staged
  do_gemm1(0, h_lds[0]);
  __syncthreads();             // h(0) ready

  for (int s = 0; s < S_N; ++s) {
    const unsigned short* hr = (const unsigned short*)h_lds[s & 1];

    // ---- fold(s-1): cw is lane-indexed -> 2 scalar LDS reads ----
    if (s > 0) {
      float cw0 = cw_lds[(s - 1) & 1][l31];
      float cw1 = cw_lds[(s - 1) & 1][32 + l31];
      #pragma unroll
      for (int r = 0; r < 16; ++r) {
        out_acc[0][r] += cw0 * acc2[0][r];
        out_acc[1][r] += cw1 * acc2[1][r];
      }
    }

    // ---- GEMM1(s+1) -> other h buffer (acc2 dead here) ----
    if (s + 1 < S_N) do_gemm1(s + 1, h_lds[(s + 1) & 1]);

    // ---- conf(s): waves 0-3; C[kidx][brow]; 2-shfl reduce ----
    if (w < 4) {
      const int crow = w * 16 + l15;
      f32x4 c3a = (f32x4){0.f, 0.f, 0.f, 0.f};
      f32x4 c3b = (f32x4){0.f, 0.f, 0.f, 0.f};
      const unsigned short* Af = Wft + ((size_t)s * K_N + l15) * H_N + g * 8;
      const unsigned cb = (unsigned)(crow * 256 + g * 16);
      #pragma unroll
      for (int ks = 0; ks < 4; ++ks) {
        bf16x8 hb = *(const bf16x8*)((const char*)hr + ((cb + ks * 64) ^ SWZ(crow)));
        c3a = MFMA16(*(const bf16x8*)(Af + ks * 32), hb, c3a);
        c3b = MFMA16(*(const bf16x8*)(Af + 16 * H_N + ks * 32), hb, c3b);
      }
      float zz = 0.f;
      {
        f32x4 bcf4 = *(const f32x4*)(bcf + s * K_N + g * 4);
        f32x4 wc4  = *(const f32x4*)(Wc2 + s * K_N + g * 4);
        #pragma unroll
        for (int i = 0; i < 4; ++i)
          zz += fmaxf(c3a[i] + bcf4[i], 0.f) * wc4[i];
        bcf4 = *(const f32x4*)(bcf + s * K_N + 16 + g * 4);
        wc4  = *(const f32x4*)(Wc2 + s * K_N + 16 + g * 4);
        #pragma unroll
        for (int i = 0; i < 4; ++i)
          zz += fmaxf(c3b[i] + bcf4[i], 0.f) * wc4[i];
      }
      zz += __shfl_xor(zz, 16);
      zz += __shfl_xor(zz, 32);
      if (l < 16) {
        float cv = lam[s] / (1.f + __expf(-(zz + bc2[s])));
        cw_lds[s & 1][w * 16 + l] = cv;
        wsum_lds[w * 16 + l] += cv;
      }
    }

    // ---- GEMM2(s): C[dcol][brow]; wave -> dcols [32w,32w+32), 2 brow tiles ----
    #pragma unroll
    for (int i = 0; i < 16; ++i) { acc2[0][i] = 0.f; acc2[1][i] = 0.f; }
    {
      const unsigned short* A2 = W2t + ((size_t)s * D_N + w * 32 + l31) * H_N + hi * 8;
      const unsigned hb0 = (unsigned)(l31 * 256 + hi * 16);
      const unsigned hb1 = (unsigned)((32 + l31) * 256 + hi * 16);
      #pragma unroll
      for (int kf = 0; kf < 8; ++kf) {
        bf16x8 aw = *(const bf16x8*)(A2 + kf * 16);
        bf16x8 h0 = *(const bf16x8*)((const char*)hr + ((hb0 + kf * 32) ^ SWZ(l31)));
        bf16x8 h1 = *(const bf16x8*)((const char*)hr + ((hb1 + kf * 32) ^ SWZ(l31)));
        acc2[0] = MFMA32(aw, h0, acc2[0]);
        acc2[1] = MFMA32(aw, h1, acc2[1]);
      }
      #pragma unroll
      for (int q = 0; q < 4; ++q) {
        f32x4 b24 = *(const f32x4*)(b2 + s * D_N + w * 32 + q * 8 + hi * 4);
        #pragma unroll
        for (int i = 0; i < 4; ++i) {
          acc2[0][q * 4 + i] += b24[i];
          acc2[1][q * 4 + i] += b24[i];
        }
      }
    }
    __syncthreads();   // single barrier per source
  }

  // ---- epilogue: fold(15), normalize, LDS-transpose, coalesced store ----
  {
    float cw0 = cw_lds[(S_N - 1) & 1][l31];
    float cw1 = cw_lds[(S_N - 1) & 1][32 + l31];
    float wi0 = 1.f / (wsum_lds[l31] + 1e-6f);
    float wi1 = 1.f / (wsum_lds[32 + l31] + 1e-6f);
    #pragma unroll
    for (int r = 0; r < 16; ++r) {
      out_acc[0][r] = (out_acc[0][r] + cw0 * acc2[0][r]) * wi0;
      out_acc[1][r] = (out_acc[1][r] + cw1 * acc2[1][r]) * wi1;
    }
  }
  {
    // per-wave 32x32 transpose region (stride 36 f32 = 4608 B, 16B aligned)
    float* tb = (w < 4 ? (float*)x_lds : (float*)h_lds) + (w & 3) * 1152;
    #pragma unroll
    for (int t = 0; t < 2; ++t) {
      __syncthreads();
      #pragma unroll
      for (int q = 0; q < 4; ++q) {
        f32x4 v;
        #pragma unroll
        for (int i = 0; i < 4; ++i) v[i] = out_acc[t][q * 4 + i];
        *(f32x4*)(tb + l31 * 36 + q * 8 + hi * 4) = v;
      }
      __syncthreads();
      #pragma unroll
      for (int p = 0; p < 2; ++p) {
        int row = (l >> 2) + p * 16;
        f32x4 v0 = *(const f32x4*)(tb + row * 36 + (l & 3) * 8);
        f32x4 v1 = *(const f32x4*)(tb + row * 36 + (l & 3) * 8 + 4);
        float* op = out + (size_t)(b0 + t * 32 + row) * D_N + w * 32 + (l & 3) * 8;
        *(f32x4*)op = v0;
        *(f32x4*)(op + 4) = v1;
      }
    }
  }
}

extern "C" void kernel_launch(void* const* d_in, const int* in_sizes, int n_in,
                              void* d_out, int out_size, void* d_ws, size_t ws_size,
                              hipStream_t stream) {
  const float* x   = (const float*)d_in[0];
  const float* W1  = (const float*)d_in[1];
  const float* b1  = (const float*)d_in[2];
  const float* W2  = (const float*)d_in[3];
  const float* b2  = (const float*)d_in[4];
  const float* Wc1 = (const float*)d_in[5];
  const float* bc1 = (const float*)d_in[6];
  const float* Wc2 = (const float*)d_in[7];
  const float* bc2 = (const float*)d_in[8];
  const float* lam = (const float*)d_in[9];
  float* out = (float*)d_out;

  // ws: W1t 1MB | W2t 1MB | Wft 128KB | bcf 2KB
  unsigned short* W1t = (unsigned short*)d_ws;
  unsigned short* W2t = W1t + (size_t)S_N * H_N * D_N;
  unsigned short* Wft = W2t + (size_t)S_N * D_N * H_N;
  float* bcf = (float*)(Wft + (size_t)S_N * K_N * H_N);

  lsi_prep<<<dim3(1152), dim3(256), 0, stream>>>(W1, W2, Wc1, b2, bc1,
                                                 W1t, W2t, Wft, bcf);
  lsi_main<<<dim3(B_N / BT), dim3(512), 0, stream>>>(x, b1, b2, Wc2, bc2, lam,
                                                     W1t, W2t, Wft, bcf, out);
}